// Round 19
// baseline (638.436 us; speedup 1.0000x reference)
//
#include <hip/hip_runtime.h>
#include <hip/hip_bf16.h>

// DomainSpecificHeads: out[b] = (hs[b] @ W_base + b_base) @ W_heads[idx[b]] + b_heads[idx[b]]
// B=8 S=512 D=1024 V=32000 ND=8 (slot ND = default head for out-of-range ids)

#define BCNT 8
#define SLEN 512
#define DDIM 1024
#define VDIM 32000
#define NDOM 8

typedef __attribute__((ext_vector_type(4))) float f32x4;
typedef __attribute__((ext_vector_type(8))) short bf16x8;

static __device__ __forceinline__ unsigned short f2bf(float f) {
    union { float f; unsigned int u; } x; x.f = f;
    unsigned int u = x.u;
    return (unsigned short)((u + 0x7FFFu + ((u >> 16) & 1u)) >> 16);  // RNE
}

// packed RNE f32x2 -> bf16x2 ; compiles to v_cvt_pk_bf16_f32
static __device__ __forceinline__ unsigned int pack2(float lo, float hi) {
    float2 t; t.x = lo; t.y = hi;
    union { __hip_bfloat162 h; unsigned int u; } c;
    c.h = __float22bfloat162_rn(t);
    return c.u;
}

#define SBAR()   __builtin_amdgcn_s_barrier()
#define SCHED0() __builtin_amdgcn_sched_barrier(0)

// ---------------- G1: hidden = hs @ W_base + b_base  (fp32 in, bf16 out) ----------------
// 128x128 tile, BK=64, 256 threads, 2x2 waves (validated round-1 structure).
__global__ __launch_bounds__(256)
void gemm1_k(const float* __restrict__ Af, const float* __restrict__ Bbase,
             const float* __restrict__ bias, __hip_bfloat16* __restrict__ Cb,
             int Mrows)
{
    __shared__ __align__(16) __hip_bfloat16 lds_a[128 * 64];
    __shared__ __align__(16) unsigned int   lds_b[32 * 128];

    const int tid  = threadIdx.x;
    const int lane = tid & 63;
    const int w    = tid >> 6;

    const int nwg = gridDim.x;
    const int bid = blockIdx.x;
    const int q   = nwg >> 3;
    const int sid = (bid & 7) * q + (bid >> 3);

    const int MT = Mrows >> 7;
    const int mt = sid % MT;
    const int nt = sid / MT;
    const int m0 = mt << 7;
    const int n0 = nt << 7;

    f32x4 acc[4][4];
    #pragma unroll
    for (int m = 0; m < 4; ++m)
        #pragma unroll
        for (int n = 0; n < 4; ++n)
            acc[m][n] = (f32x4)0.0f;

    const int wr = w >> 1, wc = w & 1;
    const int lr = lane & 15, lg = lane >> 4;

    for (int kt = 0; kt < DDIM / 64; ++kt) {
        const int kbase = kt * 64;

        #pragma unroll
        for (int t = 0; t < 8; ++t) {
            const int flat = (t * 256 + tid) * 4;
            const int row = flat >> 6, col = flat & 63;
            const float4 v = *(const float4*)(Af + (size_t)(m0 + row) * DDIM + kbase + col);
            uint2 pp;
            pp.x = pack2(v.x, v.y);
            pp.y = pack2(v.z, v.w);
            *(uint2*)(lds_a + flat) = pp;
        }

        #pragma unroll
        for (int t = 0; t < 4; ++t) {
            const int id = t * 256 + tid;
            const int kk = id >> 5;
            const int n  = (id & 31) << 2;
            const float* b0 = Bbase + (size_t)(kbase + 2 * kk) * DDIM + n0 + n;
            const float4 e = *(const float4*)b0;
            const float4 o = *(const float4*)(b0 + DDIM);
            uint4 pw;
            pw.x = pack2(e.x, o.x);
            pw.y = pack2(e.y, o.y);
            pw.z = pack2(e.z, o.z);
            pw.w = pack2(e.w, o.w);
            const int ns = n ^ ((kk & 4) << 2);
            *(uint4*)&lds_b[kk * 128 + ns] = pw;
        }

        __syncthreads();

        #pragma unroll
        for (int ks = 0; ks < 2; ++ks) {
            bf16x8 af[4], bfr[4];
            #pragma unroll
            for (int m = 0; m < 4; ++m) {
                const int row = wr * 64 + m * 16 + lr;
                const int k   = ks * 32 + lg * 8;
                af[m] = *(const bf16x8*)&lds_a[row * 64 + k];
            }
            #pragma unroll
            for (int n = 0; n < 4; ++n) {
                const int col = wc * 64 + n * 16 + lr;
                const int kkb = ks * 16 + lg * 4;
                union { unsigned int u[4]; bf16x8 v; } cvt;
                #pragma unroll
                for (int j = 0; j < 4; ++j) {
                    const int kk = kkb + j;
                    const int ns = col ^ ((kk & 4) << 2);
                    cvt.u[j] = lds_b[kk * 128 + ns];
                }
                bfr[n] = cvt.v;
            }
            #pragma unroll
            for (int m = 0; m < 4; ++m)
                #pragma unroll
                for (int n = 0; n < 4; ++n)
                    acc[m][n] = __builtin_amdgcn_mfma_f32_16x16x32_bf16(af[m], bfr[n], acc[m][n], 0, 0, 0);
        }

        __syncthreads();
    }

    #pragma unroll
    for (int m = 0; m < 4; ++m) {
        #pragma unroll
        for (int n = 0; n < 4; ++n) {
            const int col = n0 + wc * 64 + n * 16 + lr;
            const float bv = bias[col];
            #pragma unroll
            for (int r = 0; r < 4; ++r) {
                const int row = m0 + wr * 64 + m * 16 + lg * 4 + r;
                Cb[(size_t)row * DDIM + col] = __hip_bfloat16_raw{f2bf(acc[m][n][r] + bv)};
            }
        }
    }
}

// ---------------- G2: out = hidden @ W_heads[idx] + b_heads[idx] ----------------
// R19: 4-phase-per-K-tile deep pipeline (m201 template adapted to a reg-staged
// fp32 B operand), built from session-validated parts:
//  - BM=256 BN=128 BK=64, 512 threads (8 waves, 4Mx2N, 64x64 wave tiles)
//  - FULL double-buffer: 2x(32KB A + 16KB B) = 96 KB dynamic LDS, 1 block/CU
//  - per tile t: 4 phases, one acc QUADRANT (2m x 2n x 2ks = 8 MFMA) each:
//      {stage-slice issue | 8x ds_read_b128} -> SBAR -> lgkmcnt(0)+SCHED0 ->
//      setprio(1) 8 MFMA setprio(0) -> SBAR
//    stage slices: ph0/ph1 = 2 gll each (A halves -> nxt); ph2 = WRITEB(nxt)
//    (compiler vmcnt(4): drains br's 8 B(t+1) loads [oldest], keeps gll);
//    ph3 = LOADB(t+2), then ONE counted vmcnt(8) per tile before the final
//    SBAR (drains exactly the 4 nxt-A gll; 8 B(t+2) loads stay in flight
//    across tile t+1 — T4, never 0 mid-loop).
//  - dbuf removes every read-vs-write hazard on cur; each phase's ds ops
//    drain at its own lgkmcnt(0) before the owning barrier.
//  - A: gll w/ pre-swizzled source kbyte^=(row&7)<<4 + same XOR on read
//    (validated R5..R18); B: [n][kk-quad] additive-rotation slot
//    (R14-validated: zero measured bank conflicts) — T2-clean LDS is the
//    prerequisite for the phase template to pay (catalog regime-gate).
__global__ __launch_bounds__(512, 2)
void gemm2_k(const __hip_bfloat16* __restrict__ A, const float* __restrict__ Wh,
             const float* __restrict__ bh, float* __restrict__ out,
             const int* __restrict__ dom)
{
    extern __shared__ __align__(16) char smem[];
    __hip_bfloat16* ldsA0 = (__hip_bfloat16*)smem;                  // 32 KB
    __hip_bfloat16* ldsA1 = (__hip_bfloat16*)(smem + 32768);        // 32 KB
    unsigned int*   ldsB0 = (unsigned int*)(smem + 65536);          // 16 KB
    unsigned int*   ldsB1 = (unsigned int*)(smem + 81920);          // 16 KB

    const int tid  = threadIdx.x;
    const int lane = tid & 63;
    const int w    = tid >> 6;      // 0..7
    const int wr   = w >> 1;        // 0..3 -> 64-row stripe
    const int wc   = w & 1;         // 0..1 -> 64-col stripe
    const int lr   = lane & 15;
    const int lg   = lane >> 4;

    // XCD-chunked swizzle; grid = 4000 (%8==0)
    const int bid  = blockIdx.x;
    const int q    = gridDim.x >> 3;             // 500
    const int sid  = (bid & 7) * q + (bid >> 3);
    const int mt   = sid & 1;
    const int rest = sid >> 1;
    const int nt   = rest % 250;
    const int ex   = rest / 250;
    const int m0   = ex * SLEN + mt * 256;
    const int n0   = nt * 128;

    const int di  = dom[ex];
    const int hid = (di >= 0 && di < NDOM) ? di : NDOM;
    const float* Bp   = Wh + (size_t)hid * DDIM * (size_t)VDIM;
    const float* bias = bh + (size_t)hid * (size_t)VDIM;

    f32x4 acc[4][4];
    #pragma unroll
    for (int m = 0; m < 4; ++m)
        #pragma unroll
        for (int n = 0; n < 4; ++n)
            acc[m][n] = (f32x4)0.0f;

    // B staging: thread owns 8 k-rows x 2 cols (float2); 512 threads cover 64x128.
    const int nb  = (tid & 63) << 1;     // col base 0..126 (even)
    const int kb  = (tid >> 6) << 3;     // k base 0..56 (8 rows per wave)
    const int qb  = kb >> 1;             // kk-quad slot base (multiple of 4)
    const int bsw = (lane & 7) << 2;     // == ((nb>>1)&7)<<2 (nb even)
    const int bslot = ((qb ^ bsw) + (((nb >> 4) & 3) << 3)) & 31;

    float2 br[8];

    #define LOADB(KT) do {                                                         \
        const float* _p = Bp + (size_t)((KT) * 64 + kb) * VDIM + n0 + nb;          \
        _Pragma("unroll")                                                          \
        for (int j = 0; j < 8; ++j) br[j] = *(const float2*)(_p + (size_t)j * VDIM); \
    } while (0)

    #define WRITEB(LB) do {                                                        \
        uint4 w0, w1;                                                              \
        w0.x = pack2(br[0].x, br[1].x); w0.y = pack2(br[2].x, br[3].x);            \
        w0.z = pack2(br[4].x, br[5].x); w0.w = pack2(br[6].x, br[7].x);            \
        w1.x = pack2(br[0].y, br[1].y); w1.y = pack2(br[2].y, br[3].y);            \
        w1.z = pack2(br[4].y, br[5].y); w1.w = pack2(br[6].y, br[7].y);            \
        *(uint4*)&(LB)[nb * 32 + bslot]       = w0;                                \
        *(uint4*)&(LB)[(nb + 1) * 32 + bslot] = w1;                                \
    } while (0)

    // Half-stage of A: H=0 -> insts {0,1}, H=1 -> {2,3} (2 gll per wave each)
    #define STAGEA_H(LA, KT, H) do {                                               \
        _Pragma("unroll")                                                          \
        for (int i = 2*(H); i < 2*(H) + 2; ++i) {                                  \
            const int base_e = (i * 8 + w) * 512;                                  \
            const int flat   = base_e + lane * 8;                                  \
            const int row    = flat >> 6;                                          \
            const int kbyte  = (flat & 63) * 2;                                    \
            const int srck   = (kbyte ^ ((row & 7) << 4)) >> 1;                    \
            const __hip_bfloat16* src = A + (size_t)(m0 + row) * DDIM + (KT) * 64 + srck; \
            __builtin_amdgcn_global_load_lds(                                      \
                (const __attribute__((address_space(1))) unsigned int*)src,        \
                (__attribute__((address_space(3))) unsigned int*)((LA) + base_e),  \
                16, 0, 0);                                                         \
        }                                                                          \
    } while (0)

    // One phase: quadrant (QM,QN) of acc, both ks, from buffers (LA,LB).
    // Reads 4 A-frags + 4 B-frags (8x ds_read_b128), then 8 MFMAs.
    #define PHASE(QM, QN, LA, LB) do {                                             \
        bf16x8 af[2][2], bfr[2][2];                                                \
        _Pragma("unroll")                                                          \
        for (int m2 = 0; m2 < 2; ++m2) {                                           \
            const int row = wr * 64 + ((QM)*2 + m2) * 16 + lr;                     \
            _Pragma("unroll")                                                      \
            for (int ks = 0; ks < 2; ++ks) {                                       \
                const int eff = (ks * 64 + lg * 16) ^ ((row & 7) << 4);            \
                af[m2][ks] = *(const bf16x8*)&(LA)[row * 64 + (eff >> 1)];         \
            }                                                                      \
        }                                                                          \
        _Pragma("unroll")                                                          \
        for (int n2 = 0; n2 < 2; ++n2) {                                           \
            const int col = wc * 64 + ((QN)*2 + n2) * 16 + lr;                     \
            _Pragma("unroll")                                                      \
            for (int ks = 0; ks < 2; ++ks) {                                       \
                const int kkb  = ks * 16 + lg * 4;                                 \
                const int slot = ((kkb ^ (((col >> 1) & 7) << 2))                  \
                                  + (((col >> 4) & 3) << 3)) & 31;                 \
                bfr[n2][ks] = *(const bf16x8*)&(LB)[col * 32 + slot];              \
            }                                                                      \
        }                                                                          \
        SCHED0();                                                                  \
        SBAR();                                                                    \
        asm volatile("s_waitcnt lgkmcnt(0)" ::: "memory");                         \
        SCHED0();                                                                  \
        __builtin_amdgcn_s_setprio(1);                                             \
        _Pragma("unroll")                                                          \
        for (int ks = 0; ks < 2; ++ks)                                             \
            _Pragma("unroll")                                                      \
            for (int m2 = 0; m2 < 2; ++m2)                                         \
                _Pragma("unroll")                                                  \
                for (int n2 = 0; n2 < 2; ++n2)                                     \
                    acc[(QM)*2 + m2][(QN)*2 + n2] =                                \
                        __builtin_amdgcn_mfma_f32_16x16x32_bf16(                   \
                            af[m2][ks], bfr[n2][ks],                               \
                            acc[(QM)*2 + m2][(QN)*2 + n2], 0, 0, 0);               \
        __builtin_amdgcn_s_setprio(0);                                             \
        SCHED0();                                                                  \
    } while (0)

    // ---- prologue: fill buf0, leave B(1) loads in flight (R3/R5-validated) ----
    LOADB(0);
    SCHED0();
    STAGEA_H(ldsA0, 0, 0);
    STAGEA_H(ldsA0, 0, 1);
    SCHED0();
    WRITEB(ldsB0);            // compiler vmcnt drains LOADB(0)'s 8 (gll remain)
    SCHED0();
    LOADB(1);
    SCHED0();
    asm volatile("s_waitcnt vmcnt(8) lgkmcnt(0)" ::: "memory");  // drain 4 gll + ds_writes
    SCHED0();
    SBAR();

    // ---- main loop: 4 phases per K-tile, one barrier pair per phase ----
    for (int kt = 0; kt < 16; ++kt) {
        __hip_bfloat16* lA  = (kt & 1) ? ldsA1 : ldsA0;
        __hip_bfloat16* lAn = (kt & 1) ? ldsA0 : ldsA1;
        unsigned int*   lB  = (kt & 1) ? ldsB1 : ldsB0;
        unsigned int*   lBn = (kt & 1) ? ldsB0 : ldsB1;

        // phase 0: stage A half 0 -> nxt ; quadrant (0,0)
        if (kt < 15) { STAGEA_H(lAn, kt + 1, 0); SCHED0(); }
        PHASE(0, 0, lA, lB);
        SBAR();

        // phase 1: stage A half 1 -> nxt ; quadrant (0,1)
        if (kt < 15) { STAGEA_H(lAn, kt + 1, 1); SCHED0(); }
        PHASE(0, 1, lA, lB);
        SBAR();

        // phase 2: write B(t+1) -> nxt ; quadrant (1,0)
        if (kt < 15) { WRITEB(lBn); SCHED0(); }   // compiler vmcnt(4): drains br loads, keeps gll
        PHASE(1, 0, lA, lB);
        SBAR();

        // phase 3: issue B(t+2) loads ; quadrant (1,1) ; counted tile drain
        if (kt < 14) { LOADB(kt + 2); SCHED0(); }
        PHASE(1, 1, lA, lB);
        if (kt < 15) {
            if (kt < 14) asm volatile("s_waitcnt vmcnt(8)" ::: "memory");  // drain 4 gll; keep 8 B
            else         asm volatile("s_waitcnt vmcnt(0)" ::: "memory");  // no LOADB(16): drain all
            SCHED0();
            SBAR();                       // nxt tile (A+B) ready
        }
    }

    // ---- epilogue ----
    #pragma unroll
    for (int n = 0; n < 4; ++n) {
        const int col = n0 + wc * 64 + n * 16 + lr;
        const float bv = bias[col];
        #pragma unroll
        for (int m = 0; m < 4; ++m) {
            #pragma unroll
            for (int r = 0; r < 4; ++r) {
                const int row = m0 + wr * 64 + m * 16 + lg * 4 + r;
                out[(size_t)row * VDIM + col] = acc[m][n][r] + bv;
            }
        }
    }

    #undef LOADB
    #undef WRITEB
    #undef STAGEA_H
    #undef PHASE
}

extern "C" void kernel_launch(void* const* d_in, const int* in_sizes, int n_in,
                              void* d_out, int out_size, void* d_ws, size_t ws_size,
                              hipStream_t stream)
{
    const float* hs  = (const float*)d_in[0];   // [8,512,1024] fp32
    const int*   dom = (const int*)d_in[1];     // [8] int32
    const float* Wb  = (const float*)d_in[2];   // [1024,1024] fp32
    const float* bb  = (const float*)d_in[3];   // [1024] fp32
    const float* Wh  = (const float*)d_in[4];   // [9,1024,32000] fp32
    const float* bh  = (const float*)d_in[5];   // [9,32000] fp32
    float* out = (float*)d_out;                 // [8,512,32000] fp32
    __hip_bfloat16* hidden = (__hip_bfloat16*)d_ws;   // [4096,1024] bf16, 8 MB

    const int M = BCNT * SLEN;  // 4096

    // G1: 256 blocks of 256 threads
    const int g1 = (M / 128) * (DDIM / 128);
    hipLaunchKernelGGL(gemm1_k, dim3(g1), dim3(256), 0, stream, hs, Wb, bb, hidden, M);

    // G2: 8 ex * 2 mt * 250 nt = 4000 blocks of 512 threads, 96 KB dynamic LDS
    const int smem_bytes = 98304;
    static int attr_set = 0;
    if (!attr_set) {  // host-side attribute set, idempotent (R3-validated pattern)
        hipFuncSetAttribute((const void*)gemm2_k, hipFuncAttributeMaxDynamicSharedMemorySize, smem_bytes);
        attr_set = 1;
    }
    const int g2 = BCNT * (SLEN / 256) * (VDIM / 128);
    hipLaunchKernelGGL(gemm2_k, dim3(g2), dim3(512), smem_bytes, stream, hidden, Wh, bh, out, dom);
}

// Round 20
// 528.974 us; speedup vs baseline: 1.2069x; 1.2069x over previous
//
#include <hip/hip_runtime.h>
#include <hip/hip_bf16.h>

// DomainSpecificHeads: out[b] = (hs[b] @ W_base + b_base) @ W_heads[idx[b]] + b_heads[idx[b]]
// B=8 S=512 D=1024 V=32000 ND=8 (slot ND = default head for out-of-range ids)
//
// FINAL LOCKED KERNEL (== R15/R18 @ 529.4-529.7 us, verified twice).
//  Validated levers: bf16 MFMA w/ packed cvt (R1), 2-barrier K-step with
//  SCHED0-pinned clusters + counted vmcnt(8) (R3/R5, race-validated), BM=256
//  (R7), conflict-free B-slot additive rotation (R14: conflict ctr 5.3e7->0),
//  XCD-chunked example placement (iso w/ example-major, R13).
//  Falsified with counters: LDS-traffic (R11), A-latency prefetch (R12),
//  L3-thrash (R13), bank-conflict-as-critical-path (R15 null), early A-stage /
//  LDS-port contention (R16 -165us, R19 -109us), occupancy push (R17: VGPR cap
//  85 < ~132 need -> 10 GB spill), phase-split templates x3 (R8/R16/R19).
//  Plateau: serialization-bound 2-phase structure (m233); every pipe 15-45%.

#define BCNT 8
#define SLEN 512
#define DDIM 1024
#define VDIM 32000
#define NDOM 8

typedef __attribute__((ext_vector_type(4))) float f32x4;
typedef __attribute__((ext_vector_type(8))) short bf16x8;

static __device__ __forceinline__ unsigned short f2bf(float f) {
    union { float f; unsigned int u; } x; x.f = f;
    unsigned int u = x.u;
    return (unsigned short)((u + 0x7FFFu + ((u >> 16) & 1u)) >> 16);  // RNE
}

// packed RNE f32x2 -> bf16x2 ; compiles to v_cvt_pk_bf16_f32 (m240: let compiler fuse)
static __device__ __forceinline__ unsigned int pack2(float lo, float hi) {
    float2 t; t.x = lo; t.y = hi;
    union { __hip_bfloat162 h; unsigned int u; } c;
    c.h = __float22bfloat162_rn(t);
    return c.u;
}

#define SBAR()   __builtin_amdgcn_s_barrier()
#define SCHED0() __builtin_amdgcn_sched_barrier(0)

// ---------------- G1: hidden = hs @ W_base + b_base  (fp32 in, bf16 out) ----------------
// 128x128 tile, BK=64, 256 threads, 2x2 waves (validated round-1 structure).
__global__ __launch_bounds__(256)
void gemm1_k(const float* __restrict__ Af, const float* __restrict__ Bbase,
             const float* __restrict__ bias, __hip_bfloat16* __restrict__ Cb,
             int Mrows)
{
    __shared__ __align__(16) __hip_bfloat16 lds_a[128 * 64];
    __shared__ __align__(16) unsigned int   lds_b[32 * 128];

    const int tid  = threadIdx.x;
    const int lane = tid & 63;
    const int w    = tid >> 6;

    const int nwg = gridDim.x;
    const int bid = blockIdx.x;
    const int q   = nwg >> 3;
    const int sid = (bid & 7) * q + (bid >> 3);

    const int MT = Mrows >> 7;
    const int mt = sid % MT;
    const int nt = sid / MT;
    const int m0 = mt << 7;
    const int n0 = nt << 7;

    f32x4 acc[4][4];
    #pragma unroll
    for (int m = 0; m < 4; ++m)
        #pragma unroll
        for (int n = 0; n < 4; ++n)
            acc[m][n] = (f32x4)0.0f;

    const int wr = w >> 1, wc = w & 1;
    const int lr = lane & 15, lg = lane >> 4;

    for (int kt = 0; kt < DDIM / 64; ++kt) {
        const int kbase = kt * 64;

        #pragma unroll
        for (int t = 0; t < 8; ++t) {
            const int flat = (t * 256 + tid) * 4;
            const int row = flat >> 6, col = flat & 63;
            const float4 v = *(const float4*)(Af + (size_t)(m0 + row) * DDIM + kbase + col);
            uint2 pp;
            pp.x = pack2(v.x, v.y);
            pp.y = pack2(v.z, v.w);
            *(uint2*)(lds_a + flat) = pp;
        }

        #pragma unroll
        for (int t = 0; t < 4; ++t) {
            const int id = t * 256 + tid;
            const int kk = id >> 5;
            const int n  = (id & 31) << 2;
            const float* b0 = Bbase + (size_t)(kbase + 2 * kk) * DDIM + n0 + n;
            const float4 e = *(const float4*)b0;
            const float4 o = *(const float4*)(b0 + DDIM);
            uint4 pw;
            pw.x = pack2(e.x, o.x);
            pw.y = pack2(e.y, o.y);
            pw.z = pack2(e.z, o.z);
            pw.w = pack2(e.w, o.w);
            const int ns = n ^ ((kk & 4) << 2);
            *(uint4*)&lds_b[kk * 128 + ns] = pw;
        }

        __syncthreads();

        #pragma unroll
        for (int ks = 0; ks < 2; ++ks) {
            bf16x8 af[4], bfr[4];
            #pragma unroll
            for (int m = 0; m < 4; ++m) {
                const int row = wr * 64 + m * 16 + lr;
                const int k   = ks * 32 + lg * 8;
                af[m] = *(const bf16x8*)&lds_a[row * 64 + k];
            }
            #pragma unroll
            for (int n = 0; n < 4; ++n) {
                const int col = wc * 64 + n * 16 + lr;
                const int kkb = ks * 16 + lg * 4;
                union { unsigned int u[4]; bf16x8 v; } cvt;
                #pragma unroll
                for (int j = 0; j < 4; ++j) {
                    const int kk = kkb + j;
                    const int ns = col ^ ((kk & 4) << 2);
                    cvt.u[j] = lds_b[kk * 128 + ns];
                }
                bfr[n] = cvt.v;
            }
            #pragma unroll
            for (int m = 0; m < 4; ++m)
                #pragma unroll
                for (int n = 0; n < 4; ++n)
                    acc[m][n] = __builtin_amdgcn_mfma_f32_16x16x32_bf16(af[m], bfr[n], acc[m][n], 0, 0, 0);
        }

        __syncthreads();
    }

    #pragma unroll
    for (int m = 0; m < 4; ++m) {
        #pragma unroll
        for (int n = 0; n < 4; ++n) {
            const int col = n0 + wc * 64 + n * 16 + lr;
            const float bv = bias[col];
            #pragma unroll
            for (int r = 0; r < 4; ++r) {
                const int row = m0 + wr * 64 + m * 16 + lg * 4 + r;
                Cb[(size_t)row * DDIM + col] = __hip_bfloat16_raw{f2bf(acc[m][n][r] + bv)};
            }
        }
    }
}

// ---------------- G2: out = hidden @ W_heads[idx] + b_heads[idx] ----------------
// LOCKED BEST: BM=256 BN=128 BK=64, 512 threads (8 waves, 4x2 grid of 64x64
// wave tiles), single-buffered 48 KB LDS, 2 blocks/CU ((512,4)). Race-validated
// 2-barrier K-step, SCHED0-pinned clusters, counted vmcnt(8) (never 0
// mid-loop). A: global_load_lds, source pre-swizzled kbyte^=(row&7)<<4, same
// XOR on read. B: fp32 float2 loads -> bf16 k-pair u32, [n][kk-quad] layout
// with additive quad rotation (zero measured bank conflicts, write AND read).
__global__ __launch_bounds__(512, 4)
void gemm2_k(const __hip_bfloat16* __restrict__ A, const float* __restrict__ Wh,
             const float* __restrict__ bh, float* __restrict__ out,
             const int* __restrict__ dom)
{
    __shared__ __align__(16) __hip_bfloat16 ldsA[256 * 64];   // 32 KB
    __shared__ __align__(16) unsigned int   ldsB[128 * 32];   // 16 KB, [n][kk-quad] u32 k-pairs

    const int tid  = threadIdx.x;
    const int lane = tid & 63;
    const int w    = tid >> 6;      // 0..7
    const int wr   = w >> 1;        // 0..3 -> 64-row stripe
    const int wc   = w & 1;         // 0..1 -> 64-col stripe
    const int lr   = lane & 15;
    const int lg   = lane >> 4;

    // XCD-chunked swizzle; grid = 4000 (%8==0). Each XCD gets 500 consecutive sids
    // = exactly one example's full panel set; mt innermost -> 2 M-blocks per panel.
    const int bid  = blockIdx.x;
    const int q    = gridDim.x >> 3;             // 500
    const int sid  = (bid & 7) * q + (bid >> 3);
    const int mt   = sid & 1;
    const int rest = sid >> 1;
    const int nt   = rest % 250;
    const int ex   = rest / 250;
    const int m0   = ex * SLEN + mt * 256;
    const int n0   = nt * 128;

    const int di  = dom[ex];
    const int hid = (di >= 0 && di < NDOM) ? di : NDOM;
    const float* Bp   = Wh + (size_t)hid * DDIM * (size_t)VDIM;
    const float* bias = bh + (size_t)hid * (size_t)VDIM;

    f32x4 acc[4][4];
    #pragma unroll
    for (int m = 0; m < 4; ++m)
        #pragma unroll
        for (int n = 0; n < 4; ++n)
            acc[m][n] = (f32x4)0.0f;

    // B staging: thread owns 8 k-rows x 2 cols (float2); 512 threads cover 64x128.
    const int nb  = (tid & 63) << 1;     // col base 0..126 (even)
    const int kb  = (tid >> 6) << 3;     // k base 0..56 (8 rows per wave)
    const int qb  = kb >> 1;             // kk-quad slot base (multiple of 4)
    const int bsw = (lane & 7) << 2;     // == ((nb>>1)&7)<<2 (nb even -> same for nb+1)
    // Validated additive quad rotation: zero measured bank conflicts
    const int bslot = ((qb ^ bsw) + (((nb >> 4) & 3) << 3)) & 31;

    float2 br[8];

    #define LOADB(KT) do {                                                         \
        const float* _p = Bp + (size_t)((KT) * 64 + kb) * VDIM + n0 + nb;          \
        _Pragma("unroll")                                                          \
        for (int j = 0; j < 8; ++j) br[j] = *(const float2*)(_p + (size_t)j * VDIM); \
    } while (0)

    #define WRITEB() do {                                                          \
        uint4 w0, w1;                                                              \
        w0.x = pack2(br[0].x, br[1].x); w0.y = pack2(br[2].x, br[3].x);            \
        w0.z = pack2(br[4].x, br[5].x); w0.w = pack2(br[6].x, br[7].x);            \
        w1.x = pack2(br[0].y, br[1].y); w1.y = pack2(br[2].y, br[3].y);            \
        w1.z = pack2(br[4].y, br[5].y); w1.w = pack2(br[6].y, br[7].y);            \
        *(uint4*)&ldsB[nb * 32 + bslot]       = w0;                                \
        *(uint4*)&ldsB[(nb + 1) * 32 + bslot] = w1;                                \
    } while (0)

    #define STAGEA(KT) do {                                                        \
        _Pragma("unroll")                                                          \
        for (int i = 0; i < 4; ++i) {                                              \
            const int base_e = (i * 8 + w) * 512;                                  \
            const int flat   = base_e + lane * 8;                                  \
            const int row    = flat >> 6;                                          \
            const int kbyte  = (flat & 63) * 2;                                    \
            const int srck   = (kbyte ^ ((row & 7) << 4)) >> 1;                    \
            const __hip_bfloat16* src = A + (size_t)(m0 + row) * DDIM + (KT) * 64 + srck; \
            __builtin_amdgcn_global_load_lds(                                      \
                (const __attribute__((address_space(1))) unsigned int*)src,        \
                (__attribute__((address_space(3))) unsigned int*)(ldsA + base_e),  \
                16, 0, 0);                                                         \
        }                                                                          \
    } while (0)

    #define COMPUTE() do {                                                         \
        _Pragma("unroll")                                                          \
        for (int ks = 0; ks < 2; ++ks) {                                           \
            bf16x8 af[4], bfr[4];                                                  \
            _Pragma("unroll")                                                      \
            for (int m = 0; m < 4; ++m) {                                          \
                const int row = wr * 64 + m * 16 + lr;                             \
                const int kby = ks * 64 + lg * 16;                                 \
                const int eff = kby ^ ((row & 7) << 4);                            \
                af[m] = *(const bf16x8*)&ldsA[row * 64 + (eff >> 1)];              \
            }                                                                      \
            _Pragma("unroll")                                                      \
            for (int n = 0; n < 4; ++n) {                                          \
                const int col  = wc * 64 + n * 16 + lr;                            \
                const int kkb  = ks * 16 + lg * 4;                                 \
                const int slot = ((kkb ^ (((col >> 1) & 7) << 2))                  \
                                  + (((col >> 4) & 3) << 3)) & 31;                 \
                bfr[n] = *(const bf16x8*)&ldsB[col * 32 + slot];                   \
            }                                                                      \
            _Pragma("unroll")                                                      \
            for (int m = 0; m < 4; ++m)                                            \
                _Pragma("unroll")                                                  \
                for (int n = 0; n < 4; ++n)                                        \
                    acc[m][n] = __builtin_amdgcn_mfma_f32_16x16x32_bf16(af[m], bfr[n], acc[m][n], 0, 0, 0); \
        }                                                                          \
    } while (0)

    // ---- prologue (order pinned: LOADB(0) | STAGEA(0) | WRITEB | LOADB(1) | wait) ----
    LOADB(0);
    SCHED0();
    STAGEA(0);
    SCHED0();
    WRITEB();                 // compiler-inserted vmcnt drains LOADB(0)'s 8
    SCHED0();
    LOADB(1);                 // stays in flight across compute
    SCHED0();
    asm volatile("s_waitcnt vmcnt(8) lgkmcnt(0)" ::: "memory");  // drains STAGEA(0)'s 4 gll + LDS writes
    SCHED0();
    SBAR();

    // ---- main loop: compute(kt) -> barrier -> stage(kt+1) -> wait -> barrier ----
    for (int kt = 0; kt < 16; ++kt) {
        COMPUTE();
        if (kt < 15) {
            SCHED0();
            SBAR();                       // all waves done reading LDS
            SCHED0();
            STAGEA(kt + 1);               // 4x global_load_lds per wave
            SCHED0();
            WRITEB();                     // br holds B(kt+1); compiler drains its 8 loads
            SCHED0();
            if (kt < 14) {
                LOADB(kt + 2);            // 8 loads fly across next compute
                SCHED0();
                asm volatile("s_waitcnt vmcnt(8) lgkmcnt(0)" ::: "memory");
            } else {
                asm volatile("s_waitcnt vmcnt(0) lgkmcnt(0)" ::: "memory");
            }
            SCHED0();
            SBAR();
        }
    }

    // ---- epilogue ----
    #pragma unroll
    for (int n = 0; n < 4; ++n) {
        const int col = n0 + wc * 64 + n * 16 + lr;
        const float bv = bias[col];
        #pragma unroll
        for (int m = 0; m < 4; ++m) {
            #pragma unroll
            for (int r = 0; r < 4; ++r) {
                const int row = m0 + wr * 64 + m * 16 + lg * 4 + r;
                out[(size_t)row * VDIM + col] = acc[m][n][r] + bv;
            }
        }
    }

    #undef LOADB
    #undef WRITEB
    #undef STAGEA
    #undef COMPUTE
}

extern "C" void kernel_launch(void* const* d_in, const int* in_sizes, int n_in,
                              void* d_out, int out_size, void* d_ws, size_t ws_size,
                              hipStream_t stream)
{
    const float* hs  = (const float*)d_in[0];   // [8,512,1024] fp32
    const int*   dom = (const int*)d_in[1];     // [8] int32
    const float* Wb  = (const float*)d_in[2];   // [1024,1024] fp32
    const float* bb  = (const float*)d_in[3];   // [1024] fp32
    const float* Wh  = (const float*)d_in[4];   // [9,1024,32000] fp32
    const float* bh  = (const float*)d_in[5];   // [9,32000] fp32
    float* out = (float*)d_out;                 // [8,512,32000] fp32
    __hip_bfloat16* hidden = (__hip_bfloat16*)d_ws;   // [4096,1024] bf16, 8 MB

    const int M = BCNT * SLEN;  // 4096

    // G1: 256 blocks of 256 threads
    const int g1 = (M / 128) * (DDIM / 128);
    hipLaunchKernelGGL(gemm1_k, dim3(g1), dim3(256), 0, stream, hs, Wb, bb, hidden, M);

    // G2: 8 ex * 2 mt * 250 nt = 4000 blocks of 512 threads
    const int g2 = BCNT * (SLEN / 256) * (VDIM / 128);
    hipLaunchKernelGGL(gemm2_k, dim3(g2), dim3(512), 0, stream, hidden, Wh, bh, out, dom);
}